// Round 4
// baseline (141.928 us; speedup 1.0000x reference)
//
#include <hip/hip_runtime.h>
#include <hip/hip_bf16.h>
#include <stdint.h>

// ---------------------------------------------------------------------------
// VectorAttentionLayerV3: fused bf16-MFMA implementation for MI355X (gfx950)
// B=2, N=16384, M=16, C=64, H=64
//
// Math (BN folded into conv1, W1 folded through Q/K projections):
//   h   = center@Aq^T - nbr@Ak^T + pos@A1^T + b1      (Ak stored pre-negated)
//   a2  = relu(h) @ W2^T
//   w   = softmax_m(a2)
//   out = sum_m w * (nbr@Wv^T + pos)
//
// R1: GEMM1 transposed (weights as MFMA-A) so h^T lands in A-frag layout for
//     GEMM2 — no LDS round-trip / no barriers in the main loop.
// R2: 512-thread blocks -> 4 blocks/CU x 8 waves = 8 waves/SIMD (100% occ
//     ceiling, was 4); hardware v_cvt_pk_bf16_f32 packing via
//     __float22bfloat162_rn.
// R3: fix non-trivially-copyable bit_cast (memcpy bit-move instead).
// ---------------------------------------------------------------------------

#define NN 16384

typedef float f32x4 __attribute__((ext_vector_type(4)));
typedef short s16x8 __attribute__((ext_vector_type(8)));
typedef int   i32x4 __attribute__((ext_vector_type(4)));

// hot-path pack: hardware cvt_pk (RNE), 2 floats -> 1 dword of 2 bf16
__device__ __forceinline__ uint32_t pk2(float a, float b) {
  float2 f; f.x = a; f.y = b;
  __hip_bfloat162 h = __float22bfloat162_rn(f);
  uint32_t u;
  __builtin_memcpy(&u, &h, 4);
  return u;
}

__device__ __forceinline__ f32x4 mma16(i32x4 a, i32x4 b, f32x4 c) {
  return __builtin_amdgcn_mfma_f32_16x16x32_bf16(
      __builtin_bit_cast(s16x8, a), __builtin_bit_cast(s16x8, b), c, 0, 0, 0);
}

// pack two f32x4 halves (k 0..3 / k 16..19 pattern) into one bf16 fragment
__device__ __forceinline__ i32x4 packfrag(f32x4 f0, f32x4 f1) {
  i32x4 r;
  r.x = pk2(f0.x, f0.y); r.y = pk2(f0.z, f0.w);
  r.z = pk2(f1.x, f1.y); r.w = pk2(f1.z, f1.w);
  return r;
}
__device__ __forceinline__ i32x4 afrag(const float* p) {
  return packfrag(*(const f32x4*)p, *(const f32x4*)(p + 16));
}

// ---------------- weight prepass: combine, scale, pack to frag layout ------
// Packed layout (works as A-frag via rows or B-frag via cols — same mapping):
// wp[((mat*8 + kt*4 + ct)*64 + lane)*8 + e], where index16 = 16*ct + (lane&15),
// k = kt*32 + (e>=4)*16 + 4*(lane>>4) + (e&3)
__device__ __forceinline__ void wstore(uint16_t* wp, int mat, int j, int k, float v) {
  int ct = j >> 4, jl = j & 15;
  int kt = k >> 5, r = k & 31;
  int kh = r >> 4, rr = r & 15;
  int gg = rr >> 2, e2 = rr & 3;
  int lanei = jl + (gg << 4);
  int e = kh * 4 + e2;
  uint32_t u = __builtin_bit_cast(uint32_t, v);
  u += 0x7fffu + ((u >> 16) & 1u);
  wp[((mat * 8 + kt * 4 + ct) * 64 + lanei) * 8 + e] = (uint16_t)(u >> 16);
}

__global__ void prep_weights(const float* __restrict__ Wq, const float* __restrict__ Wkv,
                             const float* __restrict__ W1, const float* __restrict__ gam,
                             const float* __restrict__ bet, const float* __restrict__ mu,
                             const float* __restrict__ var, const float* __restrict__ W2,
                             uint16_t* __restrict__ wp, float* __restrict__ b1) {
  int j = blockIdx.x * 16 + (threadIdx.x >> 4);   // out index 0..63
  int q = threadIdx.x & 15;
  float gp = gam[j] * rsqrtf(var[j] + 1e-5f);
  if (q == 0) b1[j] = bet[j] - gp * mu[j];
  for (int k = q * 4; k < q * 4 + 4; ++k) {
    float aq = 0.f, ak = 0.f;
    for (int c = 0; c < 64; ++c) {
      float w1 = W1[j * 64 + c];
      aq += w1 * Wq[c * 64 + k];     // (W1·Wq)[j][k]
      ak += w1 * Wkv[c * 64 + k];    // (W1·Wk)[j][k]
    }
    wstore(wp, 0, j, k, gp * aq);                 // Aq   (A-frag rows=ch)
    wstore(wp, 1, j, k, -gp * ak);                // -Ak  (pre-negated)
    wstore(wp, 2, j, k, gp * W1[j * 64 + k]);     // A1
    wstore(wp, 3, j, k, Wkv[(64 + j) * 64 + k]);  // Wv   (B-frag cols=cv)
    wstore(wp, 4, j, k, W2[j * 64 + k]);          // W2   (B-frag cols=c2)
  }
}

// ---------------- main fused kernel ----------------------------------------
#define W_LDS_ELEMS (5 * 4096)   // 40960 B -> 4 blocks/CU (= 160 KiB exactly)

__device__ __forceinline__ i32x4 bfragld(const uint16_t* wlds, int mat, int kt, int ct, int lane) {
  return *(const i32x4*)(wlds + ((mat * 8 + kt * 4 + ct) * 64 + lane) * 8);
}

__global__ __launch_bounds__(512, 8) void vattn_main(
    const float* __restrict__ center, const float* __restrict__ nbr,
    const float* __restrict__ pos, const uint16_t* __restrict__ wp,
    const float* __restrict__ b1, float* __restrict__ out) {
  __shared__ uint16_t wlds[W_LDS_ELEMS];
  const int tid = threadIdx.x;
  {
    const i32x4* src = (const i32x4*)wp;
    i32x4* dst = (i32x4*)wlds;
#pragma unroll
    for (int i = 0; i < 5; ++i) dst[tid + 512 * i] = src[tid + 512 * i];
  }
  __syncthreads();

  const int w = tid >> 6;            // 0..7
  const int lane = tid & 63;
  const int l15 = lane & 15;
  const int g = lane >> 4;
  const int blk = blockIdx.x;
  const int b = blk >> 9;
  const int n0 = (blk & 511) << 5;   // 32 n per block
  const long nbase = (long)b * NN + n0 + (w << 2);   // this wave's first n

  // BN bias as accumulator init: lane holds channels ct*16 + 4g + r
  f32x4 binit[4];
#pragma unroll
  for (int ct = 0; ct < 4; ++ct)
#pragma unroll
    for (int r = 0; r < 4; ++r) binit[ct][r] = b1[ct * 16 + 4 * g + r];

  // double-buffered raw f32 prefetch of nbr + pos fragments
  f32x4 raw[2][8];
#define ISSUE(BUF, RT) do {                                                   \
    const float* nrp_ = nbr + (((nbase + (RT)) * 16 + l15) * 64) + g * 4;     \
    const float* prp_ = pos + (((nbase + (RT)) * 16 + l15) * 64) + g * 4;     \
    raw[BUF][0] = *(const f32x4*)nrp_;        raw[BUF][1] = *(const f32x4*)(nrp_ + 16); \
    raw[BUF][2] = *(const f32x4*)(nrp_ + 32); raw[BUF][3] = *(const f32x4*)(nrp_ + 48); \
    raw[BUF][4] = *(const f32x4*)prp_;        raw[BUF][5] = *(const f32x4*)(prp_ + 16); \
    raw[BUF][6] = *(const f32x4*)(prp_ + 32); raw[BUF][7] = *(const f32x4*)(prp_ + 48); \
  } while (0)

  ISSUE(0, 0);

#pragma unroll
  for (int rt = 0; rt < 4; ++rt) {
    if (rt < 3) ISSUE((rt + 1) & 1, rt + 1);
    const int buf = rt & 1;
    const long nrow = nbase + rt;

    // center fragments (broadcast over lanes' l15 — L1-served)
    const float* crp = center + nrow * 64 + g * 4;
    i32x4 ca0 = afrag(crp), ca1 = afrag(crp + 32);

    // pack current buffer to bf16 fragments (serve as MFMA-B: col=m=l15)
    i32x4 na0 = packfrag(raw[buf][0], raw[buf][1]);
    i32x4 na1 = packfrag(raw[buf][2], raw[buf][3]);
    i32x4 pa0 = packfrag(raw[buf][4], raw[buf][5]);
    i32x4 pa1 = packfrag(raw[buf][6], raw[buf][7]);

    // GEMM1 (transposed): h^T[ch][m], weights as A, data as B. 24 MFMAs.
    f32x4 h[4];
#pragma unroll
    for (int ct = 0; ct < 4; ++ct) {
      h[ct] = binit[ct];
      h[ct] = mma16(bfragld(wlds, 0, 0, ct, lane), ca0, h[ct]);  // Aq · center
      h[ct] = mma16(bfragld(wlds, 0, 1, ct, lane), ca1, h[ct]);
      h[ct] = mma16(bfragld(wlds, 1, 0, ct, lane), na0, h[ct]);  // -Ak · nbr
      h[ct] = mma16(bfragld(wlds, 1, 1, ct, lane), na1, h[ct]);
      h[ct] = mma16(bfragld(wlds, 2, 0, ct, lane), pa0, h[ct]);  // A1 · pos
      h[ct] = mma16(bfragld(wlds, 2, 1, ct, lane), pa1, h[ct]);
    }

    // V GEMM (untransposed): vv[m][cv], data as A, Wv as B. 8 MFMAs.
    f32x4 vv[4];
#pragma unroll
    for (int ct = 0; ct < 4; ++ct) {
      vv[ct] = (f32x4){0.f, 0.f, 0.f, 0.f};
      vv[ct] = mma16(na0, bfragld(wlds, 3, 0, ct, lane), vv[ct]);
      vv[ct] = mma16(na1, bfragld(wlds, 3, 1, ct, lane), vv[ct]);
    }

    // relu + repack: h^T C/D layout IS the A-frag layout for GEMM2
    i32x4 ha0, ha1;
    {
      f32x4 r0, r1, r2, r3;
#pragma unroll
      for (int r = 0; r < 4; ++r) {
        r0[r] = fmaxf(h[0][r], 0.f); r1[r] = fmaxf(h[1][r], 0.f);
        r2[r] = fmaxf(h[2][r], 0.f); r3[r] = fmaxf(h[3][r], 0.f);
      }
      ha0 = packfrag(r0, r1);   // k(ch) 0..31 half
      ha1 = packfrag(r2, r3);   // k(ch) 32..63 half
    }

    // GEMM2 (untransposed): a2[m][c2] = relu(h) @ W2^T. 8 MFMAs.
    f32x4 a2[4];
#pragma unroll
    for (int ct = 0; ct < 4; ++ct) {
      a2[ct] = (f32x4){0.f, 0.f, 0.f, 0.f};
      a2[ct] = mma16(ha0, bfragld(wlds, 4, 0, ct, lane), a2[ct]);
      a2[ct] = mma16(ha1, bfragld(wlds, 4, 1, ct, lane), a2[ct]);
    }

    // softmax over m (rows = 4 regs x 2 lane-group halves) + weighted sum
    const float* posrow = pos + nrow * 16 * 64;
    float ov[4];
#pragma unroll
    for (int ct = 0; ct < 4; ++ct) {
      f32x4 s = a2[ct];
      float mx = fmaxf(fmaxf(s.x, s.y), fmaxf(s.z, s.w));
      mx = fmaxf(mx, __shfl_xor(mx, 16, 64));
      mx = fmaxf(mx, __shfl_xor(mx, 32, 64));
      float e0 = __expf(s.x - mx), e1 = __expf(s.y - mx);
      float e2 = __expf(s.z - mx), e3 = __expf(s.w - mx);
      float sm = e0 + e1 + e2 + e3;
      sm += __shfl_xor(sm, 16, 64);
      sm += __shfl_xor(sm, 32, 64);
      const float* pp = posrow + (4 * g) * 64 + ct * 16 + l15;  // rows 4g+r (L1-hot)
      float ps = e0 * (vv[ct].x + pp[0])   + e1 * (vv[ct].y + pp[64]) +
                 e2 * (vv[ct].z + pp[128]) + e3 * (vv[ct].w + pp[192]);
      ps += __shfl_xor(ps, 16, 64);
      ps += __shfl_xor(ps, 32, 64);
      ov[ct] = ps / sm;
    }
    // lane = l15 + 16g stores channel c2 = 16*g + l15 = lane (coalesced)
    float val = (g == 0) ? ov[0] : (g == 1) ? ov[1] : (g == 2) ? ov[2] : ov[3];
    out[nrow * 64 + lane] = val;
  }
#undef ISSUE
}

// ---------------------------------------------------------------------------
extern "C" void kernel_launch(void* const* d_in, const int* in_sizes, int n_in,
                              void* d_out, int out_size, void* d_ws, size_t ws_size,
                              hipStream_t stream) {
  const float* center = (const float*)d_in[0];
  const float* nbr    = (const float*)d_in[1];
  const float* pos    = (const float*)d_in[2];
  const float* Wq     = (const float*)d_in[3];
  const float* Wkv    = (const float*)d_in[4];
  const float* W1     = (const float*)d_in[5];
  const float* gam    = (const float*)d_in[6];
  const float* bet    = (const float*)d_in[7];
  const float* mu     = (const float*)d_in[8];
  const float* var    = (const float*)d_in[9];
  const float* W2     = (const float*)d_in[10];
  uint16_t* wp = (uint16_t*)d_ws;
  float* b1 = (float*)((char*)d_ws + 5 * 4096 * 2);
  prep_weights<<<4, 256, 0, stream>>>(Wq, Wkv, W1, gam, bet, mu, var, W2, wp, b1);
  vattn_main<<<1024, 512, 0, stream>>>(center, nbr, pos, wp, b1, (float*)d_out);
}

// Round 5
// 122.985 us; speedup vs baseline: 1.1540x; 1.1540x over previous
//
#include <hip/hip_runtime.h>
#include <hip/hip_bf16.h>
#include <stdint.h>

// ---------------------------------------------------------------------------
// VectorAttentionLayerV3: fused bf16-MFMA implementation for MI355X (gfx950)
// B=2, N=16384, M=16, C=64, H=64
//
// Math (BN folded into conv1, W1 folded through Q/K projections):
//   h   = center@Aq^T - nbr@Ak^T + pos@A1^T + b1      (Ak stored pre-negated)
//   a2  = relu(h) @ W2^T
//   w   = softmax_m(a2)
//   out = sum_m w * (nbr@Wv^T + pos)
//
// R1: GEMM1 transposed (weights as MFMA-A) so h^T lands in A-frag layout for
//     GEMM2 — no LDS round-trip / no barriers in the main loop.
// R2: 512-thread blocks; hardware v_cvt_pk_bf16_f32 packing.
// R3: __launch_bounds__(512,8) forced VGPR<=64 -> ~78MB scratch spill, regressed.
// R4: __launch_bounds__(512,6) (budget ~85 VGPR, natural ~68 -> no spill,
//     3 blocks/CU = 6 waves/SIMD); drop explicit double-buffer (32 VGPRs) —
//     TLP, not ILP, hides latency here.
// ---------------------------------------------------------------------------

#define NN 16384

typedef float f32x4 __attribute__((ext_vector_type(4)));
typedef short s16x8 __attribute__((ext_vector_type(8)));
typedef int   i32x4 __attribute__((ext_vector_type(4)));

// hot-path pack: hardware cvt_pk (RNE), 2 floats -> 1 dword of 2 bf16
__device__ __forceinline__ uint32_t pk2(float a, float b) {
  float2 f; f.x = a; f.y = b;
  __hip_bfloat162 h = __float22bfloat162_rn(f);
  uint32_t u;
  __builtin_memcpy(&u, &h, 4);
  return u;
}

__device__ __forceinline__ f32x4 mma16(i32x4 a, i32x4 b, f32x4 c) {
  return __builtin_amdgcn_mfma_f32_16x16x32_bf16(
      __builtin_bit_cast(s16x8, a), __builtin_bit_cast(s16x8, b), c, 0, 0, 0);
}

// pack two f32x4 halves (k 0..3 / k 16..19 pattern) into one bf16 fragment
__device__ __forceinline__ i32x4 packfrag(f32x4 f0, f32x4 f1) {
  i32x4 r;
  r.x = pk2(f0.x, f0.y); r.y = pk2(f0.z, f0.w);
  r.z = pk2(f1.x, f1.y); r.w = pk2(f1.z, f1.w);
  return r;
}
__device__ __forceinline__ i32x4 afrag(const float* p) {
  return packfrag(*(const f32x4*)p, *(const f32x4*)(p + 16));
}

// ---------------- weight prepass: combine, scale, pack to frag layout ------
// Packed layout (works as A-frag via rows or B-frag via cols — same mapping):
// wp[((mat*8 + kt*4 + ct)*64 + lane)*8 + e], where index16 = 16*ct + (lane&15),
// k = kt*32 + (e>=4)*16 + 4*(lane>>4) + (e&3)
__device__ __forceinline__ void wstore(uint16_t* wp, int mat, int j, int k, float v) {
  int ct = j >> 4, jl = j & 15;
  int kt = k >> 5, r = k & 31;
  int kh = r >> 4, rr = r & 15;
  int gg = rr >> 2, e2 = rr & 3;
  int lanei = jl + (gg << 4);
  int e = kh * 4 + e2;
  uint32_t u = __builtin_bit_cast(uint32_t, v);
  u += 0x7fffu + ((u >> 16) & 1u);
  wp[((mat * 8 + kt * 4 + ct) * 64 + lanei) * 8 + e] = (uint16_t)(u >> 16);
}

__global__ void prep_weights(const float* __restrict__ Wq, const float* __restrict__ Wkv,
                             const float* __restrict__ W1, const float* __restrict__ gam,
                             const float* __restrict__ bet, const float* __restrict__ mu,
                             const float* __restrict__ var, const float* __restrict__ W2,
                             uint16_t* __restrict__ wp, float* __restrict__ b1) {
  int j = blockIdx.x * 16 + (threadIdx.x >> 4);   // out index 0..63
  int q = threadIdx.x & 15;
  float gp = gam[j] * rsqrtf(var[j] + 1e-5f);
  if (q == 0) b1[j] = bet[j] - gp * mu[j];
  for (int k = q * 4; k < q * 4 + 4; ++k) {
    float aq = 0.f, ak = 0.f;
    for (int c = 0; c < 64; ++c) {
      float w1 = W1[j * 64 + c];
      aq += w1 * Wq[c * 64 + k];     // (W1·Wq)[j][k]
      ak += w1 * Wkv[c * 64 + k];    // (W1·Wk)[j][k]
    }
    wstore(wp, 0, j, k, gp * aq);                 // Aq   (A-frag rows=ch)
    wstore(wp, 1, j, k, -gp * ak);                // -Ak  (pre-negated)
    wstore(wp, 2, j, k, gp * W1[j * 64 + k]);     // A1
    wstore(wp, 3, j, k, Wkv[(64 + j) * 64 + k]);  // Wv   (B-frag cols=cv)
    wstore(wp, 4, j, k, W2[j * 64 + k]);          // W2   (B-frag cols=c2)
  }
}

// ---------------- main fused kernel ----------------------------------------
#define W_LDS_ELEMS (5 * 4096)   // 40960 B

__device__ __forceinline__ i32x4 bfragld(const uint16_t* wlds, int mat, int kt, int ct, int lane) {
  return *(const i32x4*)(wlds + ((mat * 8 + kt * 4 + ct) * 64 + lane) * 8);
}

__global__ __launch_bounds__(512, 6) void vattn_main(
    const float* __restrict__ center, const float* __restrict__ nbr,
    const float* __restrict__ pos, const uint16_t* __restrict__ wp,
    const float* __restrict__ b1, float* __restrict__ out) {
  __shared__ uint16_t wlds[W_LDS_ELEMS];
  const int tid = threadIdx.x;
  {
    const i32x4* src = (const i32x4*)wp;
    i32x4* dst = (i32x4*)wlds;
#pragma unroll
    for (int i = 0; i < 5; ++i) dst[tid + 512 * i] = src[tid + 512 * i];
  }
  __syncthreads();

  const int w = tid >> 6;            // 0..7
  const int lane = tid & 63;
  const int l15 = lane & 15;
  const int g = lane >> 4;
  const int blk = blockIdx.x;
  const int b = blk >> 9;
  const int n0 = (blk & 511) << 5;   // 32 n per block
  const long nbase = (long)b * NN + n0 + (w << 2);   // this wave's first n

  // BN bias as accumulator init: lane holds channels ct*16 + 4g + r
  f32x4 binit[4];
#pragma unroll
  for (int ct = 0; ct < 4; ++ct)
#pragma unroll
    for (int r = 0; r < 4; ++r) binit[ct][r] = b1[ct * 16 + 4 * g + r];

#pragma unroll
  for (int rt = 0; rt < 4; ++rt) {
    const long nrow = nbase + rt;

    // data fragments: nbr/pos rows (m = l15), center broadcast (L1-served)
    const float* nrp = nbr + ((nrow * 16 + l15) * 64) + g * 4;
    const float* prp = pos + ((nrow * 16 + l15) * 64) + g * 4;
    const float* crp = center + nrow * 64 + g * 4;
    i32x4 na0 = afrag(nrp), na1 = afrag(nrp + 32);
    i32x4 pa0 = afrag(prp), pa1 = afrag(prp + 32);
    i32x4 ca0 = afrag(crp), ca1 = afrag(crp + 32);

    // GEMM1 (transposed): h^T[ch][m], weights as A, data as B. 24 MFMAs.
    f32x4 h[4];
#pragma unroll
    for (int ct = 0; ct < 4; ++ct) {
      h[ct] = binit[ct];
      h[ct] = mma16(bfragld(wlds, 0, 0, ct, lane), ca0, h[ct]);  // Aq · center
      h[ct] = mma16(bfragld(wlds, 0, 1, ct, lane), ca1, h[ct]);
      h[ct] = mma16(bfragld(wlds, 1, 0, ct, lane), na0, h[ct]);  // -Ak · nbr
      h[ct] = mma16(bfragld(wlds, 1, 1, ct, lane), na1, h[ct]);
      h[ct] = mma16(bfragld(wlds, 2, 0, ct, lane), pa0, h[ct]);  // A1 · pos
      h[ct] = mma16(bfragld(wlds, 2, 1, ct, lane), pa1, h[ct]);
    }

    // V GEMM (untransposed): vv[m][cv], data as A, Wv as B. 8 MFMAs.
    f32x4 vv[4];
#pragma unroll
    for (int ct = 0; ct < 4; ++ct) {
      vv[ct] = (f32x4){0.f, 0.f, 0.f, 0.f};
      vv[ct] = mma16(na0, bfragld(wlds, 3, 0, ct, lane), vv[ct]);
      vv[ct] = mma16(na1, bfragld(wlds, 3, 1, ct, lane), vv[ct]);
    }

    // relu + repack: h^T C/D layout IS the A-frag layout for GEMM2
    i32x4 ha0, ha1;
    {
      f32x4 r0, r1, r2, r3;
#pragma unroll
      for (int r = 0; r < 4; ++r) {
        r0[r] = fmaxf(h[0][r], 0.f); r1[r] = fmaxf(h[1][r], 0.f);
        r2[r] = fmaxf(h[2][r], 0.f); r3[r] = fmaxf(h[3][r], 0.f);
      }
      ha0 = packfrag(r0, r1);   // k(ch) 0..31 half
      ha1 = packfrag(r2, r3);   // k(ch) 32..63 half
    }

    // GEMM2 (untransposed): a2[m][c2] = relu(h) @ W2^T. 8 MFMAs.
    f32x4 a2[4];
#pragma unroll
    for (int ct = 0; ct < 4; ++ct) {
      a2[ct] = (f32x4){0.f, 0.f, 0.f, 0.f};
      a2[ct] = mma16(ha0, bfragld(wlds, 4, 0, ct, lane), a2[ct]);
      a2[ct] = mma16(ha1, bfragld(wlds, 4, 1, ct, lane), a2[ct]);
    }

    // softmax over m (rows = 4 regs x 2 lane-group halves) + weighted sum
    const float* posrow = pos + nrow * 16 * 64;
    float ov[4];
#pragma unroll
    for (int ct = 0; ct < 4; ++ct) {
      f32x4 s = a2[ct];
      float mx = fmaxf(fmaxf(s.x, s.y), fmaxf(s.z, s.w));
      mx = fmaxf(mx, __shfl_xor(mx, 16, 64));
      mx = fmaxf(mx, __shfl_xor(mx, 32, 64));
      float e0 = __expf(s.x - mx), e1 = __expf(s.y - mx);
      float e2 = __expf(s.z - mx), e3 = __expf(s.w - mx);
      float sm = e0 + e1 + e2 + e3;
      sm += __shfl_xor(sm, 16, 64);
      sm += __shfl_xor(sm, 32, 64);
      const float* pp = posrow + (4 * g) * 64 + ct * 16 + l15;  // rows 4g+r (L1-hot)
      float ps = e0 * (vv[ct].x + pp[0])   + e1 * (vv[ct].y + pp[64]) +
                 e2 * (vv[ct].z + pp[128]) + e3 * (vv[ct].w + pp[192]);
      ps += __shfl_xor(ps, 16, 64);
      ps += __shfl_xor(ps, 32, 64);
      ov[ct] = ps / sm;
    }
    // lane = l15 + 16g stores channel c2 = 16*g + l15 = lane (coalesced)
    float val = (g == 0) ? ov[0] : (g == 1) ? ov[1] : (g == 2) ? ov[2] : ov[3];
    out[nrow * 64 + lane] = val;
  }
}

// ---------------------------------------------------------------------------
extern "C" void kernel_launch(void* const* d_in, const int* in_sizes, int n_in,
                              void* d_out, int out_size, void* d_ws, size_t ws_size,
                              hipStream_t stream) {
  const float* center = (const float*)d_in[0];
  const float* nbr    = (const float*)d_in[1];
  const float* pos    = (const float*)d_in[2];
  const float* Wq     = (const float*)d_in[3];
  const float* Wkv    = (const float*)d_in[4];
  const float* W1     = (const float*)d_in[5];
  const float* gam    = (const float*)d_in[6];
  const float* bet    = (const float*)d_in[7];
  const float* mu     = (const float*)d_in[8];
  const float* var    = (const float*)d_in[9];
  const float* W2     = (const float*)d_in[10];
  uint16_t* wp = (uint16_t*)d_ws;
  float* b1 = (float*)((char*)d_ws + 5 * 4096 * 2);
  prep_weights<<<4, 256, 0, stream>>>(Wq, Wkv, W1, gam, bet, mu, var, W2, wp, b1);
  vattn_main<<<1024, 512, 0, stream>>>(center, nbr, pos, wp, b1, (float*)d_out);
}

// Round 6
// 103.617 us; speedup vs baseline: 1.3697x; 1.1869x over previous
//
#include <hip/hip_runtime.h>
#include <hip/hip_bf16.h>
#include <stdint.h>

// ---------------------------------------------------------------------------
// VectorAttentionLayerV3: fused bf16-MFMA implementation for MI355X (gfx950)
// B=2, N=16384, M=16, C=64, H=64
//
// Math (BN folded into conv1, W1 folded through Q/K projections):
//   h   = center@Aq^T - nbr@Ak^T + pos@A1^T + b1      (Ak stored pre-negated)
//   a2  = relu(h) @ W2^T
//   w   = softmax_m(a2)
//   out = sum_m w * (nbr@Wv^T + pos)
//
// R1: GEMM1 transposed (weights as MFMA-A) so h^T lands in A-frag layout for
//     GEMM2 — no LDS round-trip / no barriers in the main loop.
// R3/R4 lesson: occupancy is NOT the constraint; compiler register-
//     minimization (VGPR 40-64) serializes loads -> latency-bound at 96-141us.
// R5: batch all 4 n per wave in one straight-line block; weight fragment
//     loaded once per (mat,kt,ct) feeds 4 MFMAs (LDS reads 40/n -> 10/n);
//     __launch_bounds__(256,2) gives the scheduler a 256-VGPR budget so it
//     can hold 4 independent dep-chains + ~24 loads in flight.
// ---------------------------------------------------------------------------

#define NN 16384

typedef float f32x4 __attribute__((ext_vector_type(4)));
typedef short s16x8 __attribute__((ext_vector_type(8)));
typedef int   i32x4 __attribute__((ext_vector_type(4)));

// hot-path pack: hardware cvt_pk (RNE), 2 floats -> 1 dword of 2 bf16
__device__ __forceinline__ uint32_t pk2(float a, float b) {
  float2 f; f.x = a; f.y = b;
  __hip_bfloat162 h = __float22bfloat162_rn(f);
  uint32_t u;
  __builtin_memcpy(&u, &h, 4);
  return u;
}

__device__ __forceinline__ f32x4 mma16(i32x4 a, i32x4 b, f32x4 c) {
  return __builtin_amdgcn_mfma_f32_16x16x32_bf16(
      __builtin_bit_cast(s16x8, a), __builtin_bit_cast(s16x8, b), c, 0, 0, 0);
}

// pack two f32x4 halves (k 0..3 / k 16..19 pattern) into one bf16 fragment
__device__ __forceinline__ i32x4 packfrag(f32x4 f0, f32x4 f1) {
  i32x4 r;
  r.x = pk2(f0.x, f0.y); r.y = pk2(f0.z, f0.w);
  r.z = pk2(f1.x, f1.y); r.w = pk2(f1.z, f1.w);
  return r;
}
__device__ __forceinline__ i32x4 afrag(const float* p) {
  return packfrag(*(const f32x4*)p, *(const f32x4*)(p + 16));
}

// ---------------- weight prepass: combine, scale, pack to frag layout ------
// Packed layout (works as A-frag via rows or B-frag via cols — same mapping):
// wp[((mat*8 + kt*4 + ct)*64 + lane)*8 + e], where index16 = 16*ct + (lane&15),
// k = kt*32 + (e>=4)*16 + 4*(lane>>4) + (e&3)
__device__ __forceinline__ void wstore(uint16_t* wp, int mat, int j, int k, float v) {
  int ct = j >> 4, jl = j & 15;
  int kt = k >> 5, r = k & 31;
  int kh = r >> 4, rr = r & 15;
  int gg = rr >> 2, e2 = rr & 3;
  int lanei = jl + (gg << 4);
  int e = kh * 4 + e2;
  uint32_t u = __builtin_bit_cast(uint32_t, v);
  u += 0x7fffu + ((u >> 16) & 1u);
  wp[((mat * 8 + kt * 4 + ct) * 64 + lanei) * 8 + e] = (uint16_t)(u >> 16);
}

__global__ void prep_weights(const float* __restrict__ Wq, const float* __restrict__ Wkv,
                             const float* __restrict__ W1, const float* __restrict__ gam,
                             const float* __restrict__ bet, const float* __restrict__ mu,
                             const float* __restrict__ var, const float* __restrict__ W2,
                             uint16_t* __restrict__ wp, float* __restrict__ b1) {
  int j = blockIdx.x * 16 + (threadIdx.x >> 4);   // out index 0..63
  int q = threadIdx.x & 15;
  float gp = gam[j] * rsqrtf(var[j] + 1e-5f);
  if (q == 0) b1[j] = bet[j] - gp * mu[j];
  for (int k = q * 4; k < q * 4 + 4; ++k) {
    float aq = 0.f, ak = 0.f;
    for (int c = 0; c < 64; ++c) {
      float w1 = W1[j * 64 + c];
      aq += w1 * Wq[c * 64 + k];     // (W1·Wq)[j][k]
      ak += w1 * Wkv[c * 64 + k];    // (W1·Wk)[j][k]
    }
    wstore(wp, 0, j, k, gp * aq);                 // Aq   (A-frag rows=ch)
    wstore(wp, 1, j, k, -gp * ak);                // -Ak  (pre-negated)
    wstore(wp, 2, j, k, gp * W1[j * 64 + k]);     // A1
    wstore(wp, 3, j, k, Wkv[(64 + j) * 64 + k]);  // Wv   (B-frag cols=cv)
    wstore(wp, 4, j, k, W2[j * 64 + k]);          // W2   (B-frag cols=c2)
  }
}

// ---------------- main fused kernel ----------------------------------------
#define W_LDS_ELEMS (5 * 4096)   // 40960 B

__device__ __forceinline__ i32x4 bfragld(const uint16_t* wlds, int mat, int kt, int ct, int lane) {
  return *(const i32x4*)(wlds + ((mat * 8 + kt * 4 + ct) * 64 + lane) * 8);
}

__global__ __launch_bounds__(256, 2) void vattn_main(
    const float* __restrict__ center, const float* __restrict__ nbr,
    const float* __restrict__ pos, const uint16_t* __restrict__ wp,
    const float* __restrict__ b1, float* __restrict__ out) {
  __shared__ uint16_t wlds[W_LDS_ELEMS];
  const int tid = threadIdx.x;
  {
    const i32x4* src = (const i32x4*)wp;
    i32x4* dst = (i32x4*)wlds;
#pragma unroll
    for (int i = 0; i < 10; ++i) dst[tid + 256 * i] = src[tid + 256 * i];
  }
  __syncthreads();

  const int w = tid >> 6;            // 0..3
  const int lane = tid & 63;
  const int l15 = lane & 15;
  const int g = lane >> 4;
  const int blk = blockIdx.x;
  const int b = blk >> 10;
  const int n0 = (blk & 1023) << 4;  // 16 n per block
  const long nbase = (long)b * NN + n0 + (w << 2);   // this wave's first n

  // BN bias as accumulator init: lane holds channels ct*16 + 4g + r
  f32x4 binit[4];
#pragma unroll
  for (int ct = 0; ct < 4; ++ct)
#pragma unroll
    for (int r = 0; r < 4; ++r) binit[ct][r] = b1[ct * 16 + 4 * g + r];

  // ---- phase 0: load + pack data fragments for ALL 4 n (max MLP) ----
  i32x4 na0[4], na1[4], pa0[4], pa1[4], ca0[4], ca1[4];
#pragma unroll
  for (int j = 0; j < 4; ++j) {
    const float* nrp = nbr + (((nbase + j) * 16 + l15) * 64) + g * 4;
    const float* prp = pos + (((nbase + j) * 16 + l15) * 64) + g * 4;
    const float* crp = center + (nbase + j) * 64 + g * 4;
    na0[j] = afrag(nrp); na1[j] = afrag(nrp + 32);
    pa0[j] = afrag(prp); pa1[j] = afrag(prp + 32);
    ca0[j] = afrag(crp); ca1[j] = afrag(crp + 32);
  }

  // ---- phase 1: GEMM1 (transposed): h^T[ch][m] per n. Weight frags loaded
  //      once per (mat,kt,ct), each feeds 4 MFMAs (one per n). ----
  f32x4 h[4][4];   // [j][ct] — all indices compile-time constant
#pragma unroll
  for (int ct = 0; ct < 4; ++ct) {
    const i32x4 wq0 = bfragld(wlds, 0, 0, ct, lane);
    const i32x4 wq1 = bfragld(wlds, 0, 1, ct, lane);
    const i32x4 wk0 = bfragld(wlds, 1, 0, ct, lane);
    const i32x4 wk1 = bfragld(wlds, 1, 1, ct, lane);
    const i32x4 wp0 = bfragld(wlds, 2, 0, ct, lane);
    const i32x4 wp1 = bfragld(wlds, 2, 1, ct, lane);
#pragma unroll
    for (int j = 0; j < 4; ++j) {
      f32x4 acc = binit[ct];
      acc = mma16(wq0, ca0[j], acc);   // Aq · center
      acc = mma16(wq1, ca1[j], acc);
      acc = mma16(wk0, na0[j], acc);   // -Ak · nbr
      acc = mma16(wk1, na1[j], acc);
      acc = mma16(wp0, pa0[j], acc);   // A1 · pos
      acc = mma16(wp1, pa1[j], acc);
      h[j][ct] = acc;
    }
  }

  // ---- phase 2: relu + repack: h^T C/D layout IS the A-frag layout ----
  i32x4 ha0[4], ha1[4];
#pragma unroll
  for (int j = 0; j < 4; ++j) {
    f32x4 r0, r1, r2, r3;
#pragma unroll
    for (int r = 0; r < 4; ++r) {
      r0[r] = fmaxf(h[j][0][r], 0.f); r1[r] = fmaxf(h[j][1][r], 0.f);
      r2[r] = fmaxf(h[j][2][r], 0.f); r3[r] = fmaxf(h[j][3][r], 0.f);
    }
    ha0[j] = packfrag(r0, r1);   // k(ch) 0..31
    ha1[j] = packfrag(r2, r3);   // k(ch) 32..63
  }

  // ---- phase 3: V GEMM (untransposed): vv[m][cv] ----
  f32x4 vv[4][4];
#pragma unroll
  for (int ct = 0; ct < 4; ++ct) {
    const i32x4 wv0 = bfragld(wlds, 3, 0, ct, lane);
    const i32x4 wv1 = bfragld(wlds, 3, 1, ct, lane);
#pragma unroll
    for (int j = 0; j < 4; ++j) {
      f32x4 acc = (f32x4){0.f, 0.f, 0.f, 0.f};
      acc = mma16(na0[j], wv0, acc);
      acc = mma16(na1[j], wv1, acc);
      vv[j][ct] = acc;
    }
  }

  // ---- phase 4: GEMM2 (untransposed): a2[m][c2] = relu(h) @ W2^T ----
  f32x4 a2[4][4];
#pragma unroll
  for (int ct = 0; ct < 4; ++ct) {
    const i32x4 w20 = bfragld(wlds, 4, 0, ct, lane);
    const i32x4 w21 = bfragld(wlds, 4, 1, ct, lane);
#pragma unroll
    for (int j = 0; j < 4; ++j) {
      f32x4 acc = (f32x4){0.f, 0.f, 0.f, 0.f};
      acc = mma16(ha0[j], w20, acc);
      acc = mma16(ha1[j], w21, acc);
      a2[j][ct] = acc;
    }
  }

  // ---- phase 5: softmax over m + weighted sum of (V + pos), per n ----
#pragma unroll
  for (int j = 0; j < 4; ++j) {
    const long nrow = nbase + j;
    const float* posrow = pos + nrow * 16 * 64;
    float ov[4];
#pragma unroll
    for (int ct = 0; ct < 4; ++ct) {
      f32x4 s = a2[j][ct];
      float mx = fmaxf(fmaxf(s.x, s.y), fmaxf(s.z, s.w));
      mx = fmaxf(mx, __shfl_xor(mx, 16, 64));
      mx = fmaxf(mx, __shfl_xor(mx, 32, 64));
      float e0 = __expf(s.x - mx), e1 = __expf(s.y - mx);
      float e2 = __expf(s.z - mx), e3 = __expf(s.w - mx);
      float sm = e0 + e1 + e2 + e3;
      sm += __shfl_xor(sm, 16, 64);
      sm += __shfl_xor(sm, 32, 64);
      const float* pp = posrow + (4 * g) * 64 + ct * 16 + l15;  // rows 4g+r (L1-hot)
      float ps = e0 * (vv[j][ct].x + pp[0])   + e1 * (vv[j][ct].y + pp[64]) +
                 e2 * (vv[j][ct].z + pp[128]) + e3 * (vv[j][ct].w + pp[192]);
      ps += __shfl_xor(ps, 16, 64);
      ps += __shfl_xor(ps, 32, 64);
      ov[ct] = ps / sm;
    }
    // lane = l15 + 16g stores channel c2 = 16*g + l15 = lane (coalesced)
    float val = (g == 0) ? ov[0] : (g == 1) ? ov[1] : (g == 2) ? ov[2] : ov[3];
    out[nrow * 64 + lane] = val;
  }
}

// ---------------------------------------------------------------------------
extern "C" void kernel_launch(void* const* d_in, const int* in_sizes, int n_in,
                              void* d_out, int out_size, void* d_ws, size_t ws_size,
                              hipStream_t stream) {
  const float* center = (const float*)d_in[0];
  const float* nbr    = (const float*)d_in[1];
  const float* pos    = (const float*)d_in[2];
  const float* Wq     = (const float*)d_in[3];
  const float* Wkv    = (const float*)d_in[4];
  const float* W1     = (const float*)d_in[5];
  const float* gam    = (const float*)d_in[6];
  const float* bet    = (const float*)d_in[7];
  const float* mu     = (const float*)d_in[8];
  const float* var    = (const float*)d_in[9];
  const float* W2     = (const float*)d_in[10];
  uint16_t* wp = (uint16_t*)d_ws;
  float* b1 = (float*)((char*)d_ws + 5 * 4096 * 2);
  prep_weights<<<4, 256, 0, stream>>>(Wq, Wkv, W1, gam, bet, mu, var, W2, wp, b1);
  vattn_main<<<2048, 256, 0, stream>>>(center, nbr, pos, wp, b1, (float*)d_out);
}

// Round 7
// 102.817 us; speedup vs baseline: 1.3804x; 1.0078x over previous
//
#include <hip/hip_runtime.h>
#include <hip/hip_bf16.h>
#include <stdint.h>

// ---------------------------------------------------------------------------
// VectorAttentionLayerV3: fused bf16-MFMA implementation for MI355X (gfx950)
// B=2, N=16384, M=16, C=64, H=64
//
// Math (BN folded into conv1, W1 folded through Q/K projections):
//   h   = center@Aq^T - nbr@Ak^T + pos@A1^T + b1      (Ak stored pre-negated)
//   a2  = relu(h) @ W2^T
//   w   = softmax_m(a2)
//   out = sum_m w * (nbr@Wv^T + pos)
//
// R1: GEMM1 transposed (weights as MFMA-A) so h^T lands in A-frag layout for
//     GEMM2 — no LDS round-trip / no barriers in the main loop.
// R3-R5 lesson: occupancy knobs don't help; the invariant ~100us is the
//     per-wave serial load->use chain (compiler sinks loads to their uses).
// R6: (a) pin the pipeline: ISSUE(n+1); sched_barrier(0); compute(n) — loads
//     for the next n are architecturally in flight under current compute.
//     (b) pos-for-output prefetched in C/D layout during ISSUE and used as
//     the V-MFMA accumulator init — phase 5 has zero global loads.
// ---------------------------------------------------------------------------

#define NN 16384

typedef float f32x4 __attribute__((ext_vector_type(4)));
typedef short s16x8 __attribute__((ext_vector_type(8)));
typedef int   i32x4 __attribute__((ext_vector_type(4)));

// hot-path pack: hardware cvt_pk (RNE), 2 floats -> 1 dword of 2 bf16
__device__ __forceinline__ uint32_t pk2(float a, float b) {
  float2 f; f.x = a; f.y = b;
  __hip_bfloat162 h = __float22bfloat162_rn(f);
  uint32_t u;
  __builtin_memcpy(&u, &h, 4);
  return u;
}

__device__ __forceinline__ f32x4 mma16(i32x4 a, i32x4 b, f32x4 c) {
  return __builtin_amdgcn_mfma_f32_16x16x32_bf16(
      __builtin_bit_cast(s16x8, a), __builtin_bit_cast(s16x8, b), c, 0, 0, 0);
}

// pack two f32x4 halves (k 0..3 / k 16..19 pattern) into one bf16 fragment
__device__ __forceinline__ i32x4 packfrag(f32x4 f0, f32x4 f1) {
  i32x4 r;
  r.x = pk2(f0.x, f0.y); r.y = pk2(f0.z, f0.w);
  r.z = pk2(f1.x, f1.y); r.w = pk2(f1.z, f1.w);
  return r;
}

// ---------------- weight prepass: combine, scale, pack to frag layout ------
// Packed layout (works as A-frag via rows or B-frag via cols — same mapping):
// wp[((mat*8 + kt*4 + ct)*64 + lane)*8 + e], where index16 = 16*ct + (lane&15),
// k = kt*32 + (e>=4)*16 + 4*(lane>>4) + (e&3)
__device__ __forceinline__ void wstore(uint16_t* wp, int mat, int j, int k, float v) {
  int ct = j >> 4, jl = j & 15;
  int kt = k >> 5, r = k & 31;
  int kh = r >> 4, rr = r & 15;
  int gg = rr >> 2, e2 = rr & 3;
  int lanei = jl + (gg << 4);
  int e = kh * 4 + e2;
  uint32_t u = __builtin_bit_cast(uint32_t, v);
  u += 0x7fffu + ((u >> 16) & 1u);
  wp[((mat * 8 + kt * 4 + ct) * 64 + lanei) * 8 + e] = (uint16_t)(u >> 16);
}

__global__ void prep_weights(const float* __restrict__ Wq, const float* __restrict__ Wkv,
                             const float* __restrict__ W1, const float* __restrict__ gam,
                             const float* __restrict__ bet, const float* __restrict__ mu,
                             const float* __restrict__ var, const float* __restrict__ W2,
                             uint16_t* __restrict__ wp, float* __restrict__ b1) {
  int j = blockIdx.x * 16 + (threadIdx.x >> 4);   // out index 0..63
  int q = threadIdx.x & 15;
  float gp = gam[j] * rsqrtf(var[j] + 1e-5f);
  if (q == 0) b1[j] = bet[j] - gp * mu[j];
  for (int k = q * 4; k < q * 4 + 4; ++k) {
    float aq = 0.f, ak = 0.f;
    for (int c = 0; c < 64; ++c) {
      float w1 = W1[j * 64 + c];
      aq += w1 * Wq[c * 64 + k];     // (W1·Wq)[j][k]
      ak += w1 * Wkv[c * 64 + k];    // (W1·Wk)[j][k]
    }
    wstore(wp, 0, j, k, gp * aq);                 // Aq   (A-frag rows=ch)
    wstore(wp, 1, j, k, -gp * ak);                // -Ak  (pre-negated)
    wstore(wp, 2, j, k, gp * W1[j * 64 + k]);     // A1
    wstore(wp, 3, j, k, Wkv[(64 + j) * 64 + k]);  // Wv   (B-frag cols=cv)
    wstore(wp, 4, j, k, W2[j * 64 + k]);          // W2   (B-frag cols=c2)
  }
}

// ---------------- main fused kernel ----------------------------------------
#define W_LDS_ELEMS (5 * 4096)   // 40960 B

__device__ __forceinline__ i32x4 bfragld(const uint16_t* wlds, int mat, int kt, int ct, int lane) {
  return *(const i32x4*)(wlds + ((mat * 8 + kt * 4 + ct) * 64 + lane) * 8);
}

__global__ __launch_bounds__(256, 2) void vattn_main(
    const float* __restrict__ center, const float* __restrict__ nbr,
    const float* __restrict__ pos, const uint16_t* __restrict__ wp,
    const float* __restrict__ b1, float* __restrict__ out) {
  __shared__ uint16_t wlds[W_LDS_ELEMS];
  const int tid = threadIdx.x;
  {
    const i32x4* src = (const i32x4*)wp;
    i32x4* dst = (i32x4*)wlds;
#pragma unroll
    for (int i = 0; i < 10; ++i) dst[tid + 256 * i] = src[tid + 256 * i];
  }
  __syncthreads();

  const int w = tid >> 6;            // 0..3
  const int lane = tid & 63;
  const int l15 = lane & 15;
  const int g = lane >> 4;
  const int blk = blockIdx.x;
  const int b = blk >> 10;
  const int n0 = (blk & 1023) << 4;  // 16 n per block
  const long nbase = (long)b * NN + n0 + (w << 2);   // this wave's first n

  // BN bias as accumulator init: lane holds channels ct*16 + 4g + r
  f32x4 binit[4];
#pragma unroll
  for (int ct = 0; ct < 4; ++ct)
#pragma unroll
    for (int r = 0; r < 4; ++r) binit[ct][r] = b1[ct * 16 + 4 * g + r];

  // double-buffered raw prefetch: nbr frags, pos frags, center frags, and
  // pos in C/D layout (rq) for the V accumulator init.
  f32x4 rn[2][4], rp[2][4], rc[2][4], rq[2][4];

#define ISSUE(BUF, RT) do {                                                    \
    const long nr_ = nbase + (RT);                                             \
    const float* nrp_ = nbr + ((nr_ * 16 + l15) * 64) + g * 4;                 \
    const float* prp_ = pos + ((nr_ * 16 + l15) * 64) + g * 4;                 \
    const float* crp_ = center + nr_ * 64 + g * 4;                             \
    const float* pr_  = pos + nr_ * 1024;                                      \
    rn[BUF][0] = *(const f32x4*)nrp_;        rn[BUF][1] = *(const f32x4*)(nrp_ + 16); \
    rn[BUF][2] = *(const f32x4*)(nrp_ + 32); rn[BUF][3] = *(const f32x4*)(nrp_ + 48); \
    rp[BUF][0] = *(const f32x4*)prp_;        rp[BUF][1] = *(const f32x4*)(prp_ + 16); \
    rp[BUF][2] = *(const f32x4*)(prp_ + 32); rp[BUF][3] = *(const f32x4*)(prp_ + 48); \
    rc[BUF][0] = *(const f32x4*)crp_;        rc[BUF][1] = *(const f32x4*)(crp_ + 16); \
    rc[BUF][2] = *(const f32x4*)(crp_ + 32); rc[BUF][3] = *(const f32x4*)(crp_ + 48); \
    _Pragma("unroll")                                                          \
    for (int ct_ = 0; ct_ < 4; ++ct_)                                          \
      _Pragma("unroll")                                                        \
      for (int r_ = 0; r_ < 4; ++r_)                                           \
        rq[BUF][ct_][r_] = pr_[(4 * g + r_) * 64 + ct_ * 16 + l15];            \
    __builtin_amdgcn_sched_barrier(0);                                         \
  } while (0)

  ISSUE(0, 0);

#pragma unroll
  for (int rt = 0; rt < 4; ++rt) {
    if (rt < 3) ISSUE((rt + 1) & 1, rt + 1);   // loads pinned before compute(rt)
    const int buf = rt & 1;
    const long nrow = nbase + rt;

    // pack current buffer to bf16 fragments (MFMA-B: col=m=l15; center bcast)
    i32x4 na0 = packfrag(rn[buf][0], rn[buf][1]);
    i32x4 na1 = packfrag(rn[buf][2], rn[buf][3]);
    i32x4 pa0 = packfrag(rp[buf][0], rp[buf][1]);
    i32x4 pa1 = packfrag(rp[buf][2], rp[buf][3]);
    i32x4 ca0 = packfrag(rc[buf][0], rc[buf][1]);
    i32x4 ca1 = packfrag(rc[buf][2], rc[buf][3]);

    // GEMM1 (transposed): h^T[ch][m], weights as A, data as B. 24 MFMAs.
    f32x4 h[4];
#pragma unroll
    for (int ct = 0; ct < 4; ++ct) {
      h[ct] = binit[ct];
      h[ct] = mma16(bfragld(wlds, 0, 0, ct, lane), ca0, h[ct]);  // Aq · center
      h[ct] = mma16(bfragld(wlds, 0, 1, ct, lane), ca1, h[ct]);
      h[ct] = mma16(bfragld(wlds, 1, 0, ct, lane), na0, h[ct]);  // -Ak · nbr
      h[ct] = mma16(bfragld(wlds, 1, 1, ct, lane), na1, h[ct]);
      h[ct] = mma16(bfragld(wlds, 2, 0, ct, lane), pa0, h[ct]);  // A1 · pos
      h[ct] = mma16(bfragld(wlds, 2, 1, ct, lane), pa1, h[ct]);
    }

    // V GEMM (untransposed): vv[m][cv] = pos(C/D init) + nbr@Wv^T. 8 MFMAs.
    f32x4 vv[4];
#pragma unroll
    for (int ct = 0; ct < 4; ++ct) {
      vv[ct] = rq[buf][ct];                       // (V + pos): pos via C-init
      vv[ct] = mma16(na0, bfragld(wlds, 3, 0, ct, lane), vv[ct]);
      vv[ct] = mma16(na1, bfragld(wlds, 3, 1, ct, lane), vv[ct]);
    }

    // relu + repack: h^T C/D layout IS the A-frag layout for GEMM2
    i32x4 ha0, ha1;
    {
      f32x4 r0, r1, r2, r3;
#pragma unroll
      for (int r = 0; r < 4; ++r) {
        r0[r] = fmaxf(h[0][r], 0.f); r1[r] = fmaxf(h[1][r], 0.f);
        r2[r] = fmaxf(h[2][r], 0.f); r3[r] = fmaxf(h[3][r], 0.f);
      }
      ha0 = packfrag(r0, r1);   // k(ch) 0..31
      ha1 = packfrag(r2, r3);   // k(ch) 32..63
    }

    // GEMM2 (untransposed): a2[m][c2] = relu(h) @ W2^T. 8 MFMAs.
    f32x4 a2[4];
#pragma unroll
    for (int ct = 0; ct < 4; ++ct) {
      a2[ct] = (f32x4){0.f, 0.f, 0.f, 0.f};
      a2[ct] = mma16(ha0, bfragld(wlds, 4, 0, ct, lane), a2[ct]);
      a2[ct] = mma16(ha1, bfragld(wlds, 4, 1, ct, lane), a2[ct]);
    }

    // softmax over m + weighted sum — all in-register now (no global loads)
    float ov[4];
#pragma unroll
    for (int ct = 0; ct < 4; ++ct) {
      f32x4 s = a2[ct];
      float mx = fmaxf(fmaxf(s.x, s.y), fmaxf(s.z, s.w));
      mx = fmaxf(mx, __shfl_xor(mx, 16, 64));
      mx = fmaxf(mx, __shfl_xor(mx, 32, 64));
      float e0 = __expf(s.x - mx), e1 = __expf(s.y - mx);
      float e2 = __expf(s.z - mx), e3 = __expf(s.w - mx);
      float sm = e0 + e1 + e2 + e3;
      sm += __shfl_xor(sm, 16, 64);
      sm += __shfl_xor(sm, 32, 64);
      float ps = e0 * vv[ct].x + e1 * vv[ct].y + e2 * vv[ct].z + e3 * vv[ct].w;
      ps += __shfl_xor(ps, 16, 64);
      ps += __shfl_xor(ps, 32, 64);
      ov[ct] = ps / sm;
    }
    // lane = l15 + 16g stores channel c2 = 16*g + l15 = lane (coalesced)
    float val = (g == 0) ? ov[0] : (g == 1) ? ov[1] : (g == 2) ? ov[2] : ov[3];
    out[nrow * 64 + lane] = val;
  }
#undef ISSUE
}

// ---------------------------------------------------------------------------
extern "C" void kernel_launch(void* const* d_in, const int* in_sizes, int n_in,
                              void* d_out, int out_size, void* d_ws, size_t ws_size,
                              hipStream_t stream) {
  const float* center = (const float*)d_in[0];
  const float* nbr    = (const float*)d_in[1];
  const float* pos    = (const float*)d_in[2];
  const float* Wq     = (const float*)d_in[3];
  const float* Wkv    = (const float*)d_in[4];
  const float* W1     = (const float*)d_in[5];
  const float* gam    = (const float*)d_in[6];
  const float* bet    = (const float*)d_in[7];
  const float* mu     = (const float*)d_in[8];
  const float* var    = (const float*)d_in[9];
  const float* W2     = (const float*)d_in[10];
  uint16_t* wp = (uint16_t*)d_ws;
  float* b1 = (float*)((char*)d_ws + 5 * 4096 * 2);
  prep_weights<<<4, 256, 0, stream>>>(Wq, Wkv, W1, gam, bet, mu, var, W2, wp, b1);
  vattn_main<<<2048, 256, 0, stream>>>(center, nbr, pos, wp, b1, (float*)d_out);
}